// Round 5
// baseline (77.116 us; speedup 1.0000x reference)
//
#include <hip/hip_runtime.h>
#include <hip/hip_bf16.h>
#include <math.h>

#define D_SINGLE 512
#define D_PAIR   128
#define RANK     32
#define NROW     512
#define EPS      1e-5f

typedef __attribute__((ext_vector_type(8))) short bf16x8;  // 8 bf16 = 4 VGPRs
typedef __attribute__((ext_vector_type(4))) float f32x4;

// ---------------------------------------------------------------------------
// Kernel 1: per-row LayerNorm + low-rank projection for both inputs.
// a-side output stored as bf16 (feeds k3 MFMA B-frag), b-side as f32 (feeds k2).
// ---------------------------------------------------------------------------
__global__ __launch_bounds__(256) void k1_ln_proj(
    const float* __restrict__ xa, const float* __restrict__ xb,
    const float* __restrict__ ln_g, const float* __restrict__ ln_b,
    const float* __restrict__ wl, const float* __restrict__ bl,
    const float* __restrict__ wr, const float* __restrict__ br,
    __hip_bfloat16* __restrict__ a_bf, float* __restrict__ b_proj)
{
    const int bid  = blockIdx.x;
    const int row  = bid & (NROW - 1);
    const bool isb = bid >= NROW;
    const float* x    = (isb ? xb : xa) + row * D_SINGLE;
    const float* W    = isb ? wr : wl;
    const float* bias = isb ? br : bl;
    float*           outf = b_proj + row * RANK;
    __hip_bfloat16*  outh = a_bf   + row * RANK;

    __shared__ float xn[D_SINGLE];
    __shared__ float red[8];

    const int t    = threadIdx.x;
    const int wave = t >> 6;
    const int lane = t & 63;

    float x0 = x[t], x1 = x[t + 256];
    float s  = x0 + x1;
    float ss = x0 * x0 + x1 * x1;
    #pragma unroll
    for (int m = 1; m < 64; m <<= 1) {
        s  += __shfl_xor(s, m);
        ss += __shfl_xor(ss, m);
    }
    if (lane == 0) { red[wave] = s; red[4 + wave] = ss; }
    __syncthreads();
    float S    = red[0] + red[1] + red[2] + red[3];
    float SS   = red[4] + red[5] + red[6] + red[7];
    float mean = S * (1.0f / D_SINGLE);
    float var  = SS * (1.0f / D_SINGLE) - mean * mean;
    float rstd = rsqrtf(var + EPS);
    xn[t]       = (x0 - mean) * rstd * ln_g[t]       + ln_b[t];
    xn[t + 256] = (x1 - mean) * rstd * ln_g[t + 256] + ln_b[t + 256];
    __syncthreads();

    #pragma unroll
    for (int q = 0; q < 8; ++q) {
        int r = wave + 4 * q;
        float acc = 0.f;
        #pragma unroll
        for (int tt = 0; tt < 8; ++tt) {
            int k = lane + 64 * tt;
            acc += xn[k] * W[r * D_SINGLE + k];
        }
        #pragma unroll
        for (int m = 1; m < 64; m <<= 1) acc += __shfl_xor(acc, m);
        if (lane == 0) {
            float v = acc + bias[r];
            if (isb) outf[r] = v;
            else     outh[r] = __float2bfloat16(v);
        }
    }
}

// ---------------------------------------------------------------------------
// Kernel 2: wb[j][p*32+r] = sum_s b[j][s] * w_out[p][r*32+s], stored bf16.
// ---------------------------------------------------------------------------
__global__ __launch_bounds__(256) void k2_wb(
    const float* __restrict__ bproj, const float* __restrict__ w_out,
    __hip_bfloat16* __restrict__ wb)
{
    const int g = blockIdx.x >> 4;   // j-group (8 rows of b)
    const int c = blockIdx.x & 15;   // pr chunk
    const int t = threadIdx.x;

    __shared__ float bl[8 * RANK];
    bl[t] = bproj[g * 8 * RANK + t];
    __syncthreads();

    const int pr = c * 256 + t;
    const int p  = pr >> 5;
    const int r  = pr & 31;

    const float4* wrow = reinterpret_cast<const float4*>(w_out + p * (RANK * RANK) + r * RANK);
    float4 w[8];
    #pragma unroll
    for (int q = 0; q < 8; ++q) w[q] = wrow[q];

    #pragma unroll
    for (int jj = 0; jj < 8; ++jj) {
        float acc = 0.f;
        #pragma unroll
        for (int q = 0; q < 8; ++q) {
            acc += bl[jj * 32 + 4 * q + 0] * w[q].x
                 + bl[jj * 32 + 4 * q + 1] * w[q].y
                 + bl[jj * 32 + 4 * q + 2] * w[q].z
                 + bl[jj * 32 + 4 * q + 3] * w[q].w;
        }
        wb[(size_t)(g * 8 + jj) * 4096 + pr] = __float2bfloat16(acc);
    }
}

// ---------------------------------------------------------------------------
// Kernel 3 (MFMA, NI=4): D[p,i] = WB_j[p,r] * a^T[r,i] + b_out[p], LN over p.
// One wave per (j, 4 consecutive 16-row i-blocks): af (wb slice), C-in bias
// and LN gamma/beta loaded ONCE, reused for 4 i-blocks -> ~3x fewer VMEM
// issues per output vs round 4. 8 MFMAs per i-block (p=0..127, K=32).
// C/D map: row(p) = (lane>>4)*4+reg, col(i) = lane&15 (m89-verified).
// ---------------------------------------------------------------------------
__global__ __launch_bounds__(256, 4) void k3_mfma(
    const __hip_bfloat16* __restrict__ a_bf, const __hip_bfloat16* __restrict__ wb_bf,
    const float* __restrict__ b_out, const float* __restrict__ lno_g,
    const float* __restrict__ lno_b, float* __restrict__ out)
{
    const int t    = threadIdx.x;
    const int wv   = t >> 6;
    const int lane = t & 63;
    const int g    = lane >> 4;
    const int c    = lane & 15;
    const int j     = blockIdx.x & (NROW - 1);
    const int chunk = blockIdx.x >> 9;          // 0..1
    const int ib0   = chunk * 16 + wv * 4;      // first of 4 i-blocks

    const short* a_s = reinterpret_cast<const short*>(a_bf);
    const short* wbj = reinterpret_cast<const short*>(wb_bf) + (size_t)j * 4096;

    // Prefetch the 4 B-frags (a rows), then the wb slice (A-frags).
    bf16x8 bfrag[4];
    #pragma unroll
    for (int n = 0; n < 4; ++n) {
        const int i0 = (ib0 + n) * 16 + c;
        bfrag[n] = *reinterpret_cast<const bf16x8*>(a_s + i0 * RANK + g * 8);
    }
    bf16x8 af[8];
    #pragma unroll
    for (int tt = 0; tt < 8; ++tt)
        af[tt] = *reinterpret_cast<const bf16x8*>(wbj + (tt * 16 + c) * RANK + g * 8);

    // Uniform per-p vectors (same across i-blocks).
    f32x4 cin[8], gm[8], bt[8];
    #pragma unroll
    for (int tt = 0; tt < 8; ++tt) {
        cin[tt] = *reinterpret_cast<const f32x4*>(b_out + tt * 16 + g * 4);
        gm[tt]  = *reinterpret_cast<const f32x4*>(lno_g + tt * 16 + g * 4);
        bt[tt]  = *reinterpret_cast<const f32x4*>(lno_b + tt * 16 + g * 4);
    }

    #pragma unroll
    for (int n = 0; n < 4; ++n) {
        const int i0 = (ib0 + n) * 16 + c;
        f32x4 acc[8];
        #pragma unroll
        for (int tt = 0; tt < 8; ++tt)
            acc[tt] = __builtin_amdgcn_mfma_f32_16x16x32_bf16(af[tt], bfrag[n], cin[tt], 0, 0, 0);

        float s = 0.f, ss = 0.f;
        #pragma unroll
        for (int tt = 0; tt < 8; ++tt) {
            #pragma unroll
            for (int r = 0; r < 4; ++r) { float v = acc[tt][r]; s += v; ss += v * v; }
        }
        s  += __shfl_xor(s, 16);  ss += __shfl_xor(ss, 16);
        s  += __shfl_xor(s, 32);  ss += __shfl_xor(ss, 32);
        const float mean = s * (1.0f / D_PAIR);
        const float var  = ss * (1.0f / D_PAIR) - mean * mean;
        const float rstd = rsqrtf(var + EPS);

        float* obase = out + ((size_t)i0 * NROW + j) * D_PAIR;
        #pragma unroll
        for (int tt = 0; tt < 8; ++tt) {
            f32x4 o;
            #pragma unroll
            for (int r = 0; r < 4; ++r)
                o[r] = (acc[tt][r] - mean) * rstd * gm[tt][r] + bt[tt][r];
            *reinterpret_cast<f32x4*>(obase + tt * 16 + g * 4) = o;
        }
    }
}

// ---------------------------------------------------------------------------
extern "C" void kernel_launch(void* const* d_in, const int* in_sizes, int n_in,
                              void* d_out, int out_size, void* d_ws, size_t ws_size,
                              hipStream_t stream) {
    const float* single_a = (const float*)d_in[0];
    const float* single_b = (const float*)d_in[1];
    const float* ln_g     = (const float*)d_in[2];
    const float* ln_b     = (const float*)d_in[3];
    const float* w_left   = (const float*)d_in[4];
    const float* b_left   = (const float*)d_in[5];
    const float* w_right  = (const float*)d_in[6];
    const float* b_right  = (const float*)d_in[7];
    const float* w_out    = (const float*)d_in[8];
    const float* b_out    = (const float*)d_in[9];
    const float* lno_g    = (const float*)d_in[10];
    const float* lno_b    = (const float*)d_in[11];
    float* out = (float*)d_out;

    float* ws = (float*)d_ws;
    __hip_bfloat16* a_bf   = (__hip_bfloat16*)ws;                    // 512*32 bf16 = 32 KB
    float*          b_proj = ws + 16384;                             // 512*32 f32
    __hip_bfloat16* wb_bf  = (__hip_bfloat16*)(ws + 32768);          // 512*4096 bf16 = 4 MB

    k1_ln_proj<<<2 * NROW, 256, 0, stream>>>(single_a, single_b, ln_g, ln_b,
                                             w_left, b_left, w_right, b_right,
                                             a_bf, b_proj);
    k2_wb<<<1024, 256, 0, stream>>>(b_proj, w_out, wb_bf);
    k3_mfma<<<1024, 256, 0, stream>>>(a_bf, wb_bf, b_out, lno_g, lno_b, out);
}

// Round 6
// 76.396 us; speedup vs baseline: 1.0094x; 1.0094x over previous
//
#include <hip/hip_runtime.h>
#include <hip/hip_bf16.h>
#include <math.h>

#define D_SINGLE 512
#define D_PAIR   128
#define RANK     32
#define NROW     512
#define EPS      1e-5f

typedef __attribute__((ext_vector_type(8))) short bf16x8;  // 8 bf16 = 4 VGPRs
typedef __attribute__((ext_vector_type(4))) float f32x4;

// ---------------------------------------------------------------------------
// Kernel 1: per-row LayerNorm + low-rank projection for both inputs.
// a-side output stored as bf16 (feeds k3 MFMA B-frag), b-side as f32 (feeds k2).
// ---------------------------------------------------------------------------
__global__ __launch_bounds__(256) void k1_ln_proj(
    const float* __restrict__ xa, const float* __restrict__ xb,
    const float* __restrict__ ln_g, const float* __restrict__ ln_b,
    const float* __restrict__ wl, const float* __restrict__ bl,
    const float* __restrict__ wr, const float* __restrict__ br,
    __hip_bfloat16* __restrict__ a_bf, float* __restrict__ b_proj)
{
    const int bid  = blockIdx.x;
    const int row  = bid & (NROW - 1);
    const bool isb = bid >= NROW;
    const float* x    = (isb ? xb : xa) + row * D_SINGLE;
    const float* W    = isb ? wr : wl;
    const float* bias = isb ? br : bl;
    float*           outf = b_proj + row * RANK;
    __hip_bfloat16*  outh = a_bf   + row * RANK;

    __shared__ float xn[D_SINGLE];
    __shared__ float red[8];

    const int t    = threadIdx.x;
    const int wave = t >> 6;
    const int lane = t & 63;

    float x0 = x[t], x1 = x[t + 256];
    float s  = x0 + x1;
    float ss = x0 * x0 + x1 * x1;
    #pragma unroll
    for (int m = 1; m < 64; m <<= 1) {
        s  += __shfl_xor(s, m);
        ss += __shfl_xor(ss, m);
    }
    if (lane == 0) { red[wave] = s; red[4 + wave] = ss; }
    __syncthreads();
    float S    = red[0] + red[1] + red[2] + red[3];
    float SS   = red[4] + red[5] + red[6] + red[7];
    float mean = S * (1.0f / D_SINGLE);
    float var  = SS * (1.0f / D_SINGLE) - mean * mean;
    float rstd = rsqrtf(var + EPS);
    xn[t]       = (x0 - mean) * rstd * ln_g[t]       + ln_b[t];
    xn[t + 256] = (x1 - mean) * rstd * ln_g[t + 256] + ln_b[t + 256];
    __syncthreads();

    #pragma unroll
    for (int q = 0; q < 8; ++q) {
        int r = wave + 4 * q;
        float acc = 0.f;
        #pragma unroll
        for (int tt = 0; tt < 8; ++tt) {
            int k = lane + 64 * tt;
            acc += xn[k] * W[r * D_SINGLE + k];
        }
        #pragma unroll
        for (int m = 1; m < 64; m <<= 1) acc += __shfl_xor(acc, m);
        if (lane == 0) {
            float v = acc + bias[r];
            if (isb) outf[r] = v;
            else     outh[r] = __float2bfloat16(v);
        }
    }
}

// ---------------------------------------------------------------------------
// Kernel 2: wb[j][p*32+r] = sum_s b[j][s] * w_out[p][r*32+s], stored bf16.
// ---------------------------------------------------------------------------
__global__ __launch_bounds__(256) void k2_wb(
    const float* __restrict__ bproj, const float* __restrict__ w_out,
    __hip_bfloat16* __restrict__ wb)
{
    const int g = blockIdx.x >> 4;   // j-group (8 rows of b)
    const int c = blockIdx.x & 15;   // pr chunk
    const int t = threadIdx.x;

    __shared__ float bl[8 * RANK];
    bl[t] = bproj[g * 8 * RANK + t];
    __syncthreads();

    const int pr = c * 256 + t;
    const int p  = pr >> 5;
    const int r  = pr & 31;

    const float4* wrow = reinterpret_cast<const float4*>(w_out + p * (RANK * RANK) + r * RANK);
    float4 w[8];
    #pragma unroll
    for (int q = 0; q < 8; ++q) w[q] = wrow[q];

    #pragma unroll
    for (int jj = 0; jj < 8; ++jj) {
        float acc = 0.f;
        #pragma unroll
        for (int q = 0; q < 8; ++q) {
            acc += bl[jj * 32 + 4 * q + 0] * w[q].x
                 + bl[jj * 32 + 4 * q + 1] * w[q].y
                 + bl[jj * 32 + 4 * q + 2] * w[q].z
                 + bl[jj * 32 + 4 * q + 3] * w[q].w;
        }
        wb[(size_t)(g * 8 + jj) * 4096 + pr] = __float2bfloat16(acc);
    }
}

// ---------------------------------------------------------------------------
// Kernel 3 (MFMA, persistent-j): one block (512 thr, 8 waves) per j.
// Wave wv, step n: i-block = n*8+wv  -> at step n the block's 8 waves write
// a contiguous 128-row i-slab; all 512 resident blocks sweep i together
// (tight chip-wide HBM write window, vs 128 MB random in round 4).
// af (wb_j slice) + cin loaded ONCE per wave, reused over 4 steps.
// gm/bt reloaded per step (L1) to stay under the 128-VGPR cap (round-5
// lesson: caching them spilled). 8 MFMAs per step (p=0..127, K=32).
// C/D map: row(p) = (lane>>4)*4+reg, col(i) = lane&15 (m89-verified).
// ---------------------------------------------------------------------------
__global__ __launch_bounds__(512, 4) void k3_mfma(
    const __hip_bfloat16* __restrict__ a_bf, const __hip_bfloat16* __restrict__ wb_bf,
    const float* __restrict__ b_out, const float* __restrict__ lno_g,
    const float* __restrict__ lno_b, float* __restrict__ out)
{
    const int t    = threadIdx.x;
    const int wv   = t >> 6;          // 0..7
    const int lane = t & 63;
    const int g    = lane >> 4;
    const int c    = lane & 15;
    const int j    = blockIdx.x;      // 0..511

    const short* a_s = reinterpret_cast<const short*>(a_bf);
    const short* wbj = reinterpret_cast<const short*>(wb_bf) + (size_t)j * 4096;

    // Load once per wave: wb_j slice (A-frags) + bias C-in.
    bf16x8 af[8];
    f32x4  cin[8];
    #pragma unroll
    for (int tt = 0; tt < 8; ++tt) {
        af[tt]  = *reinterpret_cast<const bf16x8*>(wbj + (tt * 16 + c) * RANK + g * 8);
        cin[tt] = *reinterpret_cast<const f32x4*>(b_out + tt * 16 + g * 4);
    }

    #pragma unroll
    for (int n = 0; n < 4; ++n) {
        const int ib = n * 8 + wv;           // i-block 0..31
        const int i0 = ib * 16 + c;          // this lane's i (col)
        bf16x8 bfrag = *reinterpret_cast<const bf16x8*>(a_s + i0 * RANK + g * 8);

        f32x4 acc[8];
        #pragma unroll
        for (int tt = 0; tt < 8; ++tt)
            acc[tt] = __builtin_amdgcn_mfma_f32_16x16x32_bf16(af[tt], bfrag, cin[tt], 0, 0, 0);

        float s = 0.f, ss = 0.f;
        #pragma unroll
        for (int tt = 0; tt < 8; ++tt) {
            #pragma unroll
            for (int r = 0; r < 4; ++r) { float v = acc[tt][r]; s += v; ss += v * v; }
        }
        s  += __shfl_xor(s, 16);  ss += __shfl_xor(ss, 16);
        s  += __shfl_xor(s, 32);  ss += __shfl_xor(ss, 32);
        const float mean = s * (1.0f / D_PAIR);
        const float var  = ss * (1.0f / D_PAIR) - mean * mean;
        const float rstd = rsqrtf(var + EPS);

        float* obase = out + ((size_t)i0 * NROW + j) * D_PAIR;
        #pragma unroll
        for (int tt = 0; tt < 8; ++tt) {
            f32x4 gm = *reinterpret_cast<const f32x4*>(lno_g + tt * 16 + g * 4);
            f32x4 bt = *reinterpret_cast<const f32x4*>(lno_b + tt * 16 + g * 4);
            f32x4 o;
            #pragma unroll
            for (int r = 0; r < 4; ++r)
                o[r] = (acc[tt][r] - mean) * rstd * gm[r] + bt[r];
            *reinterpret_cast<f32x4*>(obase + tt * 16 + g * 4) = o;
        }
    }
}

// ---------------------------------------------------------------------------
extern "C" void kernel_launch(void* const* d_in, const int* in_sizes, int n_in,
                              void* d_out, int out_size, void* d_ws, size_t ws_size,
                              hipStream_t stream) {
    const float* single_a = (const float*)d_in[0];
    const float* single_b = (const float*)d_in[1];
    const float* ln_g     = (const float*)d_in[2];
    const float* ln_b     = (const float*)d_in[3];
    const float* w_left   = (const float*)d_in[4];
    const float* b_left   = (const float*)d_in[5];
    const float* w_right  = (const float*)d_in[6];
    const float* b_right  = (const float*)d_in[7];
    const float* w_out    = (const float*)d_in[8];
    const float* b_out    = (const float*)d_in[9];
    const float* lno_g    = (const float*)d_in[10];
    const float* lno_b    = (const float*)d_in[11];
    float* out = (float*)d_out;

    float* ws = (float*)d_ws;
    __hip_bfloat16* a_bf   = (__hip_bfloat16*)ws;                    // 512*32 bf16 = 32 KB
    float*          b_proj = ws + 16384;                             // 512*32 f32
    __hip_bfloat16* wb_bf  = (__hip_bfloat16*)(ws + 32768);          // 512*4096 bf16 = 4 MB

    k1_ln_proj<<<2 * NROW, 256, 0, stream>>>(single_a, single_b, ln_g, ln_b,
                                             w_left, b_left, w_right, b_right,
                                             a_bf, b_proj);
    k2_wb<<<1024, 256, 0, stream>>>(b_proj, w_out, wb_bf);
    k3_mfma<<<NROW, 512, 0, stream>>>(a_bf, wb_bf, b_out, lno_g, lno_b, out);
}

// Round 7
// 49.245 us; speedup vs baseline: 1.5660x; 1.5513x over previous
//
#include <hip/hip_runtime.h>
#include <hip/hip_bf16.h>
#include <math.h>

#define D_SINGLE 512
#define D_PAIR   128
#define RANK     32
#define NROW     512
#define EPS      1e-5f

typedef __attribute__((ext_vector_type(8))) short bf16x8;  // 8 bf16 = 4 VGPRs
typedef __attribute__((ext_vector_type(4))) float f32x4;

// ---------------------------------------------------------------------------
// Kernel 1: per-row LayerNorm + low-rank projection for both inputs.
// a-side output stored as bf16 (feeds k3 MFMA B-frag), b-side as f32 (feeds k2).
// ---------------------------------------------------------------------------
__global__ __launch_bounds__(256) void k1_ln_proj(
    const float* __restrict__ xa, const float* __restrict__ xb,
    const float* __restrict__ ln_g, const float* __restrict__ ln_b,
    const float* __restrict__ wl, const float* __restrict__ bl,
    const float* __restrict__ wr, const float* __restrict__ br,
    __hip_bfloat16* __restrict__ a_bf, float* __restrict__ b_proj)
{
    const int bid  = blockIdx.x;
    const int row  = bid & (NROW - 1);
    const bool isb = bid >= NROW;
    const float* x    = (isb ? xb : xa) + row * D_SINGLE;
    const float* W    = isb ? wr : wl;
    const float* bias = isb ? br : bl;
    float*           outf = b_proj + row * RANK;
    __hip_bfloat16*  outh = a_bf   + row * RANK;

    __shared__ float xn[D_SINGLE];
    __shared__ float red[8];

    const int t    = threadIdx.x;
    const int wave = t >> 6;
    const int lane = t & 63;

    float x0 = x[t], x1 = x[t + 256];
    float s  = x0 + x1;
    float ss = x0 * x0 + x1 * x1;
    #pragma unroll
    for (int m = 1; m < 64; m <<= 1) {
        s  += __shfl_xor(s, m);
        ss += __shfl_xor(ss, m);
    }
    if (lane == 0) { red[wave] = s; red[4 + wave] = ss; }
    __syncthreads();
    float S    = red[0] + red[1] + red[2] + red[3];
    float SS   = red[4] + red[5] + red[6] + red[7];
    float mean = S * (1.0f / D_SINGLE);
    float var  = SS * (1.0f / D_SINGLE) - mean * mean;
    float rstd = rsqrtf(var + EPS);
    xn[t]       = (x0 - mean) * rstd * ln_g[t]       + ln_b[t];
    xn[t + 256] = (x1 - mean) * rstd * ln_g[t + 256] + ln_b[t + 256];
    __syncthreads();

    #pragma unroll
    for (int q = 0; q < 8; ++q) {
        int r = wave + 4 * q;
        float acc = 0.f;
        #pragma unroll
        for (int tt = 0; tt < 8; ++tt) {
            int k = lane + 64 * tt;
            acc += xn[k] * W[r * D_SINGLE + k];
        }
        #pragma unroll
        for (int m = 1; m < 64; m <<= 1) acc += __shfl_xor(acc, m);
        if (lane == 0) {
            float v = acc + bias[r];
            if (isb) outf[r] = v;
            else     outh[r] = __float2bfloat16(v);
        }
    }
}

// ---------------------------------------------------------------------------
// Kernel 2: wb[j][p*32+r] = sum_s b[j][s] * w_out[p][r*32+s], stored bf16.
// ---------------------------------------------------------------------------
__global__ __launch_bounds__(256) void k2_wb(
    const float* __restrict__ bproj, const float* __restrict__ w_out,
    __hip_bfloat16* __restrict__ wb)
{
    const int g = blockIdx.x >> 4;   // j-group (8 rows of b)
    const int c = blockIdx.x & 15;   // pr chunk
    const int t = threadIdx.x;

    __shared__ float bl[8 * RANK];
    bl[t] = bproj[g * 8 * RANK + t];
    __syncthreads();

    const int pr = c * 256 + t;
    const int p  = pr >> 5;
    const int r  = pr & 31;

    const float4* wrow = reinterpret_cast<const float4*>(w_out + p * (RANK * RANK) + r * RANK);
    float4 w[8];
    #pragma unroll
    for (int q = 0; q < 8; ++q) w[q] = wrow[q];

    #pragma unroll
    for (int jj = 0; jj < 8; ++jj) {
        float acc = 0.f;
        #pragma unroll
        for (int q = 0; q < 8; ++q) {
            acc += bl[jj * 32 + 4 * q + 0] * w[q].x
                 + bl[jj * 32 + 4 * q + 1] * w[q].y
                 + bl[jj * 32 + 4 * q + 2] * w[q].z
                 + bl[jj * 32 + 4 * q + 3] * w[q].w;
        }
        wb[(size_t)(g * 8 + jj) * 4096 + pr] = __float2bfloat16(acc);
    }
}

// ---------------------------------------------------------------------------
// Kernel 3 (MFMA + LDS-staged coalesced stores).
// Block = 256 thr (4 waves), one (i-block of 16, j-quad) tile.
// Phase 1: wave wv computes j = j0+wv via 8 MFMAs (transient af/cin loads --
//   the r4 register pattern the allocator handles well), LN over p in-wave,
//   writes normalized tile to LDS [16 i][4 j][128 p] with XOR-swizzled slots.
// Phase 2: cooperative sweep -- each wave instruction stores 1 KB contiguous;
//   the block emits dense 2 KB (4 j x 512 B) per output row instead of r4's
//   isolated 512-B bursts at 256-KB stride (HBM page-locality fix).
// Grid: jt fast (bid&127) => XCD x touches only j === x (mod 8): 512 KB wb
//   slice stays L2-resident per XCD.
// C/D map: p = tt*16 + g*4 + r, i = i0 + c (m89-verified, passed r4/r5/r6).
// ---------------------------------------------------------------------------
__global__ __launch_bounds__(256, 4) void k3_mfma(
    const __hip_bfloat16* __restrict__ a_bf, const __hip_bfloat16* __restrict__ wb_bf,
    const float* __restrict__ b_out, const float* __restrict__ lno_g,
    const float* __restrict__ lno_b, float* __restrict__ out)
{
    const int t    = threadIdx.x;
    const int wv   = t >> 6;          // 0..3 -> j within quad
    const int lane = t & 63;
    const int g    = lane >> 4;
    const int c    = lane & 15;
    const int jt   = blockIdx.x & 127;   // fast dim -> XCD j-locality
    const int ib   = blockIdx.x >> 7;    // 0..31
    const int j0   = jt * 4;
    const int i0   = ib * 16;
    const int j    = j0 + wv;

    __shared__ __align__(16) float L[16 * 4 * D_PAIR];   // 32 KB

    const short* a_s = reinterpret_cast<const short*>(a_bf);
    const short* wbj = reinterpret_cast<const short*>(wb_bf) + (size_t)j * 4096;

    // ---- Phase 1: MFMA + LN (all operand loads transient) ----
    bf16x8 bfrag = *reinterpret_cast<const bf16x8*>(a_s + (i0 + c) * RANK + g * 8);

    f32x4 acc[8];
    #pragma unroll
    for (int tt = 0; tt < 8; ++tt) {
        bf16x8 af  = *reinterpret_cast<const bf16x8*>(wbj + (tt * 16 + c) * RANK + g * 8);
        f32x4  cin = *reinterpret_cast<const f32x4*>(b_out + tt * 16 + g * 4);
        acc[tt] = __builtin_amdgcn_mfma_f32_16x16x32_bf16(af, bfrag, cin, 0, 0, 0);
    }

    float s = 0.f, ss = 0.f;
    #pragma unroll
    for (int tt = 0; tt < 8; ++tt) {
        #pragma unroll
        for (int r = 0; r < 4; ++r) { float v = acc[tt][r]; s += v; ss += v * v; }
    }
    s  += __shfl_xor(s, 16);  ss += __shfl_xor(ss, 16);
    s  += __shfl_xor(s, 32);  ss += __shfl_xor(ss, 32);
    const float mean = s * (1.0f / D_PAIR);
    const float var  = ss * (1.0f / D_PAIR) - mean * mean;
    const float rstd = rsqrtf(var + EPS);

    // normalized tile -> LDS, slot-swizzled (bits 4..6 ^= i&7): keeps both
    // fragment-order writes and linear sweep reads at the b128 8-cycle minimum
    #pragma unroll
    for (int tt = 0; tt < 8; ++tt) {
        f32x4 gm = *reinterpret_cast<const f32x4*>(lno_g + tt * 16 + g * 4);
        f32x4 bt = *reinterpret_cast<const f32x4*>(lno_b + tt * 16 + g * 4);
        f32x4 o;
        #pragma unroll
        for (int r = 0; r < 4; ++r)
            o[r] = (acc[tt][r] - mean) * rstd * gm[r] + bt[r];
        int off = c * 2048 + wv * 512 + tt * 64 + g * 16;   // bytes
        off ^= (c & 7) << 4;
        *reinterpret_cast<f32x4*>(reinterpret_cast<char*>(L) + off) = o;
    }
    __syncthreads();

    // ---- Phase 2: coalesced sweep store ----
    const int f     = t & 127;        // 128 threads cover one i-row (2 KB)
    const int ihalf = t >> 7;         // 2 rows per round
    #pragma unroll
    for (int rnd = 0; rnd < 8; ++rnd) {
        const int i = rnd * 2 + ihalf;
        int off = i * 2048 + f * 16;
        off ^= (i & 7) << 4;
        f32x4 v = *reinterpret_cast<const f32x4*>(reinterpret_cast<const char*>(L) + off);
        float* dst = out + (size_t)(i0 + i) * (NROW * D_PAIR) + j0 * D_PAIR + f * 4;
        *reinterpret_cast<f32x4*>(dst) = v;
    }
}

// ---------------------------------------------------------------------------
extern "C" void kernel_launch(void* const* d_in, const int* in_sizes, int n_in,
                              void* d_out, int out_size, void* d_ws, size_t ws_size,
                              hipStream_t stream) {
    const float* single_a = (const float*)d_in[0];
    const float* single_b = (const float*)d_in[1];
    const float* ln_g     = (const float*)d_in[2];
    const float* ln_b     = (const float*)d_in[3];
    const float* w_left   = (const float*)d_in[4];
    const float* b_left   = (const float*)d_in[5];
    const float* w_right  = (const float*)d_in[6];
    const float* b_right  = (const float*)d_in[7];
    const float* w_out    = (const float*)d_in[8];
    const float* b_out    = (const float*)d_in[9];
    const float* lno_g    = (const float*)d_in[10];
    const float* lno_b    = (const float*)d_in[11];
    float* out = (float*)d_out;

    float* ws = (float*)d_ws;
    __hip_bfloat16* a_bf   = (__hip_bfloat16*)ws;                    // 512*32 bf16 = 32 KB
    float*          b_proj = ws + 16384;                             // 512*32 f32
    __hip_bfloat16* wb_bf  = (__hip_bfloat16*)(ws + 32768);          // 512*4096 bf16 = 4 MB

    k1_ln_proj<<<2 * NROW, 256, 0, stream>>>(single_a, single_b, ln_g, ln_b,
                                             w_left, b_left, w_right, b_right,
                                             a_bf, b_proj);
    k2_wb<<<1024, 256, 0, stream>>>(b_proj, w_out, wb_bf);
    k3_mfma<<<4096, 256, 0, stream>>>(a_bf, wb_bf, b_out, lno_g, lno_b, out);
}

// Round 8
// 45.829 us; speedup vs baseline: 1.6827x; 1.0745x over previous
//
#include <hip/hip_runtime.h>
#include <hip/hip_bf16.h>
#include <math.h>

#define D_SINGLE 512
#define D_PAIR   128
#define RANK     32
#define NROW     512
#define EPS      1e-5f

typedef __attribute__((ext_vector_type(8))) short bf16x8;  // 8 bf16 = 4 VGPRs
typedef __attribute__((ext_vector_type(4))) float f32x4;

// ---------------------------------------------------------------------------
// Kernel 1: per-row LayerNorm + low-rank projection for both inputs.
// a-side output stored as bf16 (feeds k3 MFMA B-frag), b-side as f32 (feeds k2).
// ---------------------------------------------------------------------------
__global__ __launch_bounds__(256) void k1_ln_proj(
    const float* __restrict__ xa, const float* __restrict__ xb,
    const float* __restrict__ ln_g, const float* __restrict__ ln_b,
    const float* __restrict__ wl, const float* __restrict__ bl,
    const float* __restrict__ wr, const float* __restrict__ br,
    __hip_bfloat16* __restrict__ a_bf, float* __restrict__ b_proj)
{
    const int bid  = blockIdx.x;
    const int row  = bid & (NROW - 1);
    const bool isb = bid >= NROW;
    const float* x    = (isb ? xb : xa) + row * D_SINGLE;
    const float* W    = isb ? wr : wl;
    const float* bias = isb ? br : bl;
    float*           outf = b_proj + row * RANK;
    __hip_bfloat16*  outh = a_bf   + row * RANK;

    __shared__ float xn[D_SINGLE];
    __shared__ float red[8];

    const int t    = threadIdx.x;
    const int wave = t >> 6;
    const int lane = t & 63;

    float x0 = x[t], x1 = x[t + 256];
    float s  = x0 + x1;
    float ss = x0 * x0 + x1 * x1;
    #pragma unroll
    for (int m = 1; m < 64; m <<= 1) {
        s  += __shfl_xor(s, m);
        ss += __shfl_xor(ss, m);
    }
    if (lane == 0) { red[wave] = s; red[4 + wave] = ss; }
    __syncthreads();
    float S    = red[0] + red[1] + red[2] + red[3];
    float SS   = red[4] + red[5] + red[6] + red[7];
    float mean = S * (1.0f / D_SINGLE);
    float var  = SS * (1.0f / D_SINGLE) - mean * mean;
    float rstd = rsqrtf(var + EPS);
    xn[t]       = (x0 - mean) * rstd * ln_g[t]       + ln_b[t];
    xn[t + 256] = (x1 - mean) * rstd * ln_g[t + 256] + ln_b[t + 256];
    __syncthreads();

    #pragma unroll
    for (int q = 0; q < 8; ++q) {
        int r = wave + 4 * q;
        float acc = 0.f;
        #pragma unroll
        for (int tt = 0; tt < 8; ++tt) {
            int k = lane + 64 * tt;
            acc += xn[k] * W[r * D_SINGLE + k];
        }
        #pragma unroll
        for (int m = 1; m < 64; m <<= 1) acc += __shfl_xor(acc, m);
        if (lane == 0) {
            float v = acc + bias[r];
            if (isb) outf[r] = v;
            else     outh[r] = __float2bfloat16(v);
        }
    }
}

// ---------------------------------------------------------------------------
// Kernel 2: wb[j][p*32+r] = sum_s b[j][s] * w_out[p][r*32+s], stored bf16.
// ---------------------------------------------------------------------------
__global__ __launch_bounds__(256) void k2_wb(
    const float* __restrict__ bproj, const float* __restrict__ w_out,
    __hip_bfloat16* __restrict__ wb)
{
    const int g = blockIdx.x >> 4;   // j-group (8 rows of b)
    const int c = blockIdx.x & 15;   // pr chunk
    const int t = threadIdx.x;

    __shared__ float bl[8 * RANK];
    bl[t] = bproj[g * 8 * RANK + t];
    __syncthreads();

    const int pr = c * 256 + t;
    const int p  = pr >> 5;
    const int r  = pr & 31;

    const float4* wrow = reinterpret_cast<const float4*>(w_out + p * (RANK * RANK) + r * RANK);
    float4 w[8];
    #pragma unroll
    for (int q = 0; q < 8; ++q) w[q] = wrow[q];

    #pragma unroll
    for (int jj = 0; jj < 8; ++jj) {
        float acc = 0.f;
        #pragma unroll
        for (int q = 0; q < 8; ++q) {
            acc += bl[jj * 32 + 4 * q + 0] * w[q].x
                 + bl[jj * 32 + 4 * q + 1] * w[q].y
                 + bl[jj * 32 + 4 * q + 2] * w[q].z
                 + bl[jj * 32 + 4 * q + 3] * w[q].w;
        }
        wb[(size_t)(g * 8 + jj) * 4096 + pr] = __float2bfloat16(acc);
    }
}

// ---------------------------------------------------------------------------
// Kernel 3 (MFMA + LDS-staged stores + NONTEMPORAL writes).
// Identical to round 7 except phase-2 stores use __builtin_nontemporal_store
// (global_store_dwordx4 nt): the 128 MB output stream bypasses per-XCD L2
// write-back allocation -> stores reach HBM in issue order (dense bursts,
// like fillBuffer's 6.9 TB/s stream) instead of scrambled eviction order,
// and wb slices stop being evicted from L2 by the stream.
// C/D map: p = tt*16 + g*4 + r, i = i0 + c (m89-verified, passed r4-r7).
// ---------------------------------------------------------------------------
__global__ __launch_bounds__(256, 4) void k3_mfma(
    const __hip_bfloat16* __restrict__ a_bf, const __hip_bfloat16* __restrict__ wb_bf,
    const float* __restrict__ b_out, const float* __restrict__ lno_g,
    const float* __restrict__ lno_b, float* __restrict__ out)
{
    const int t    = threadIdx.x;
    const int wv   = t >> 6;          // 0..3 -> j within quad
    const int lane = t & 63;
    const int g    = lane >> 4;
    const int c    = lane & 15;
    const int jt   = blockIdx.x & 127;   // fast dim -> XCD j-locality
    const int ib   = blockIdx.x >> 7;    // 0..31
    const int j0   = jt * 4;
    const int i0   = ib * 16;
    const int j    = j0 + wv;

    __shared__ __align__(16) float L[16 * 4 * D_PAIR];   // 32 KB

    const short* a_s = reinterpret_cast<const short*>(a_bf);
    const short* wbj = reinterpret_cast<const short*>(wb_bf) + (size_t)j * 4096;

    // ---- Phase 1: MFMA + LN (all operand loads transient) ----
    bf16x8 bfrag = *reinterpret_cast<const bf16x8*>(a_s + (i0 + c) * RANK + g * 8);

    f32x4 acc[8];
    #pragma unroll
    for (int tt = 0; tt < 8; ++tt) {
        bf16x8 af  = *reinterpret_cast<const bf16x8*>(wbj + (tt * 16 + c) * RANK + g * 8);
        f32x4  cin = *reinterpret_cast<const f32x4*>(b_out + tt * 16 + g * 4);
        acc[tt] = __builtin_amdgcn_mfma_f32_16x16x32_bf16(af, bfrag, cin, 0, 0, 0);
    }

    float s = 0.f, ss = 0.f;
    #pragma unroll
    for (int tt = 0; tt < 8; ++tt) {
        #pragma unroll
        for (int r = 0; r < 4; ++r) { float v = acc[tt][r]; s += v; ss += v * v; }
    }
    s  += __shfl_xor(s, 16);  ss += __shfl_xor(ss, 16);
    s  += __shfl_xor(s, 32);  ss += __shfl_xor(ss, 32);
    const float mean = s * (1.0f / D_PAIR);
    const float var  = ss * (1.0f / D_PAIR) - mean * mean;
    const float rstd = rsqrtf(var + EPS);

    // normalized tile -> LDS, slot-swizzled (bits 4..6 ^= i&7)
    #pragma unroll
    for (int tt = 0; tt < 8; ++tt) {
        f32x4 gm = *reinterpret_cast<const f32x4*>(lno_g + tt * 16 + g * 4);
        f32x4 bt = *reinterpret_cast<const f32x4*>(lno_b + tt * 16 + g * 4);
        f32x4 o;
        #pragma unroll
        for (int r = 0; r < 4; ++r)
            o[r] = (acc[tt][r] - mean) * rstd * gm[r] + bt[r];
        int off = c * 2048 + wv * 512 + tt * 64 + g * 16;   // bytes
        off ^= (c & 7) << 4;
        *reinterpret_cast<f32x4*>(reinterpret_cast<char*>(L) + off) = o;
    }
    __syncthreads();

    // ---- Phase 2: coalesced nontemporal sweep store ----
    const int f     = t & 127;        // 128 threads cover one i-row (2 KB)
    const int ihalf = t >> 7;         // 2 rows per round
    #pragma unroll
    for (int rnd = 0; rnd < 8; ++rnd) {
        const int i = rnd * 2 + ihalf;
        int off = i * 2048 + f * 16;
        off ^= (i & 7) << 4;
        f32x4 v = *reinterpret_cast<const f32x4*>(reinterpret_cast<const char*>(L) + off);
        float* dst = out + (size_t)(i0 + i) * (NROW * D_PAIR) + j0 * D_PAIR + f * 4;
        __builtin_nontemporal_store(v, reinterpret_cast<f32x4*>(dst));
    }
}

// ---------------------------------------------------------------------------
extern "C" void kernel_launch(void* const* d_in, const int* in_sizes, int n_in,
                              void* d_out, int out_size, void* d_ws, size_t ws_size,
                              hipStream_t stream) {
    const float* single_a = (const float*)d_in[0];
    const float* single_b = (const float*)d_in[1];
    const float* ln_g     = (const float*)d_in[2];
    const float* ln_b     = (const float*)d_in[3];
    const float* w_left   = (const float*)d_in[4];
    const float* b_left   = (const float*)d_in[5];
    const float* w_right  = (const float*)d_in[6];
    const float* b_right  = (const float*)d_in[7];
    const float* w_out    = (const float*)d_in[8];
    const float* b_out    = (const float*)d_in[9];
    const float* lno_g    = (const float*)d_in[10];
    const float* lno_b    = (const float*)d_in[11];
    float* out = (float*)d_out;

    float* ws = (float*)d_ws;
    __hip_bfloat16* a_bf   = (__hip_bfloat16*)ws;                    // 512*32 bf16 = 32 KB
    float*          b_proj = ws + 16384;                             // 512*32 f32
    __hip_bfloat16* wb_bf  = (__hip_bfloat16*)(ws + 32768);          // 512*4096 bf16 = 4 MB

    k1_ln_proj<<<2 * NROW, 256, 0, stream>>>(single_a, single_b, ln_g, ln_b,
                                             w_left, b_left, w_right, b_right,
                                             a_bf, b_proj);
    k2_wb<<<1024, 256, 0, stream>>>(b_proj, w_out, wb_bf);
    k3_mfma<<<4096, 256, 0, stream>>>(a_bf, wb_bf, b_out, lno_g, lno_b, out);
}